// Round 9
// baseline (284.617 us; speedup 1.0000x reference)
//
#include <hip/hip_runtime.h>

// GCN 2-layer, round 9: fused AGG1+GEMM2 with LEAN gather + wave-local epilogue.
// r8 lesson: 4-deep clamped-masked gather + int-div W2 staging + per-block
// barrier made agg1f issue-bound (VALUBusy 77%, 80us vs r7's 57.7). Fix:
//  - gather loop = r7's 2-deep unmasked form;
//  - epilogue is per-wave (no barriers in node loop): post-butterfly every
//    lane holds full sums for its fl group -> bias+relu in-lane, then 32x
//    { __shfl broadcast + W2s LDS read (2-way, free) + fma }, one
//    shfl_xor(32) to combine halves;
//  - W2 staged to LDS once per block (i>>5 / i&31, no div), grid-stride
//    2048 blocks so staging runs 2048x not 25000x.
// CSR build unchanged (LDS-staged burst-flush scatter, zero global atomics).
// Transform-first identity: segsum(h[src]) @ W == segsum((h@W)[src]).

#define NN 100000
#define NE 3200000
#define NOUTF 30
#define TPB 256
#define TPBW 1024                          // hist blocks
#define TPBS 512                           // scatter blocks
#define AGG1_BLOCKS 2048

// dst stream buckets
#define DSH 8
#define DCB 256
#define DNB ((NN + DCB - 1) / DCB)         // 391
// src stream buckets
#define SSH 10
#define SCB 1024
#define SNB ((NN + SCB - 1) / SCB)         // 98

#define CHUNK 8192
#define NBLK ((NE + CHUNK - 1) / CHUNK)    // 391
#define HLD (DNB * NBLK)                   // 152,881
#define HLS (SNB * NBLK)                   // 38,318
#define HLT (HLD + HLS)                    // 191,199
#define EPT (CHUNK / TPBS)                 // 16 edges per scatter thread

#define GCH 1024
#define NSC ((HLT + GCH - 1) / GCH)        // 187

#define POOL 9216                          // fine-sort staging (36KB LDS)

__device__ __forceinline__ unsigned short f2bf(float f) {  // round-nearest-even
  unsigned u = __float_as_uint(f);
  u = (u + 0x7FFFu + ((u >> 16) & 1u)) >> 16;
  return (unsigned short)u;
}

// accumulate 8 bf16 (one uint4) into 8 f32
__device__ __forceinline__ void acc8(float* a, const uint4& u) {
  a[0] += __uint_as_float(u.x << 16);
  a[1] += __uint_as_float(u.x & 0xFFFF0000u);
  a[2] += __uint_as_float(u.y << 16);
  a[3] += __uint_as_float(u.y & 0xFFFF0000u);
  a[4] += __uint_as_float(u.z << 16);
  a[5] += __uint_as_float(u.z & 0xFFFF0000u);
  a[6] += __uint_as_float(u.w << 16);
  a[7] += __uint_as_float(u.w & 0xFFFF0000u);
}

// bijective XCD swizzle (m204 variant): consecutive swizzled ids -> same XCD
__device__ __forceinline__ int xcd_swz(int orig, int n) {
  int q = n / 8, r = n % 8;
  int xcd = orig % 8, idx = orig / 8;
  return (xcd < r ? xcd * (q + 1) : r * (q + 1) + (xcd - r) * q) + idx;
}

// ------ A: dual coarse histogram (dst>>8 and src>>10, LDS only) -------------
__global__ __launch_bounds__(TPBW) void k_hist(const int* __restrict__ src,
                                               const int* __restrict__ dst,
                                               int* __restrict__ H) {
  __shared__ int hd[DNB], hs[SNB];
  int t = threadIdx.x, k = blockIdx.x;
  for (int b = t; b < DNB; b += TPBW) hd[b] = 0;
  for (int b = t; b < SNB; b += TPBW) hs[b] = 0;
  __syncthreads();
  int beg = k * CHUNK, end = min(NE, beg + CHUNK);
  for (int i = beg + t; i < end; i += TPBW) {
    atomicAdd(&hd[dst[i] >> DSH], 1);
    atomicAdd(&hs[src[i] >> SSH], 1);
  }
  __syncthreads();
  for (int b = t; b < DNB; b += TPBW) H[b * NBLK + k] = hd[b];
  for (int b = t; b < SNB; b += TPBW) H[HLD + b * NBLK + k] = hs[b];
}

// ------ B: 3-kernel exclusive scan over H[HLT] -------------------------------
__global__ __launch_bounds__(TPB) void g_scan1(const int* __restrict__ a,
                                               int* __restrict__ bsums) {
  int t = threadIdx.x;
  int base = blockIdx.x * GCH + t * 4;
  int s = 0;
#pragma unroll
  for (int j = 0; j < 4; ++j) { int idx = base + j; if (idx < HLT) s += a[idx]; }
  __shared__ int red[TPB];
  red[t] = s; __syncthreads();
  for (int off = TPB / 2; off > 0; off >>= 1) {
    if (t < off) red[t] += red[t + off];
    __syncthreads();
  }
  if (t == 0) bsums[blockIdx.x] = red[0];
}

__global__ __launch_bounds__(1024) void g_scan2(int* __restrict__ bsums) {
  int t = threadIdx.x;
  __shared__ int lds[1024];
  int v = (t < NSC) ? bsums[t] : 0;
  int acc = v; lds[t] = acc; __syncthreads();
  for (int off = 1; off < 1024; off <<= 1) {
    int add = (t >= off) ? lds[t - off] : 0; __syncthreads();
    acc += add; lds[t] = acc; __syncthreads();
  }
  if (t < NSC) bsums[t] = acc - v;  // exclusive
}

__global__ __launch_bounds__(TPB) void g_scan3(int* __restrict__ a,
                                               const int* __restrict__ bsums) {
  int t = threadIdx.x;
  int base = blockIdx.x * GCH + t * 4;
  int v[4]; int s = 0;
#pragma unroll
  for (int j = 0; j < 4; ++j) {
    int idx = base + j;
    v[j] = (idx < HLT) ? a[idx] : 0;
    s += v[j];
  }
  __shared__ int lds[TPB];
  int acc = s; lds[t] = acc; __syncthreads();
  for (int off = 1; off < TPB; off <<= 1) {
    int add = (t >= off) ? lds[t - off] : 0; __syncthreads();
    acc += add; lds[t] = acc; __syncthreads();
  }
  int run = bsums[blockIdx.x] + (acc - s);
#pragma unroll
  for (int j = 0; j < 4; ++j) {
    int idx = base + j;
    if (idx < HLT) a[idx] = run;  // in-place exclusive
    run += v[j];
  }
}

// ------ C: LDS-staged dual scatter with contiguous burst flush --------------
__global__ __launch_bounds__(TPBS) void k_scatter(const int* __restrict__ src,
                                                  const int* __restrict__ dst,
                                                  const int* __restrict__ Hsc,
                                                  int* __restrict__ packed,
                                                  unsigned short* __restrict__ ss) {
  __shared__ int pack_lds[CHUNK];            // 32KB
  __shared__ unsigned short ss_lds[CHUNK];   // 16KB
  __shared__ int baseD[DNB + 1], curD[DNB];
  __shared__ int baseS[SNB + 1], curS[SNB];
  __shared__ int scanbuf[TPBS];
  int t = threadIdx.x;
  int k = xcd_swz((int)blockIdx.x, NBLK);    // adjacent chunks -> same XCD
  int beg = k * CHUNK, end = min(NE, beg + CHUNK);
  int cnt = end - beg;

  // register-stage this chunk's edges (coalesced reads, read once)
  int es[EPT], ed[EPT];
#pragma unroll
  for (int j = 0; j < EPT; ++j) {
    int i = beg + j * TPBS + t;
    if (i < end) { es[j] = src[i]; ed[j] = dst[i]; }
    else { es[j] = -1; ed[j] = -1; }
  }

  // block-local histograms (curD/curS double as hist accumulators)
  for (int b = t; b < DNB; b += TPBS) curD[b] = 0;
  for (int b = t; b < SNB; b += TPBS) curS[b] = 0;
  __syncthreads();
#pragma unroll
  for (int j = 0; j < EPT; ++j) {
    if (ed[j] >= 0) {
      atomicAdd(&curD[ed[j] >> DSH], 1);
      atomicAdd(&curS[es[j] >> SSH], 1);
    }
  }
  __syncthreads();

  // exclusive scan of curD -> baseD (DNB=391 <= TPBS)
  {
    int v = (t < DNB) ? curD[t] : 0;
    int acc = v; scanbuf[t] = acc; __syncthreads();
    for (int off = 1; off < TPBS; off <<= 1) {
      int add = (t >= off) ? scanbuf[t - off] : 0; __syncthreads();
      acc += add; scanbuf[t] = acc; __syncthreads();
    }
    if (t < DNB) baseD[t] = acc - v;
    if (t == 0) baseD[DNB] = cnt;
  }
  __syncthreads();
  // exclusive scan of curS -> baseS (SNB=98)
  {
    int v = (t < SNB) ? curS[t] : 0;
    int acc = v; scanbuf[t] = acc; __syncthreads();
    for (int off = 1; off < TPBS; off <<= 1) {
      int add = (t >= off) ? scanbuf[t - off] : 0; __syncthreads();
      acc += add; scanbuf[t] = acc; __syncthreads();
    }
    if (t < SNB) baseS[t] = acc - v;
    if (t == 0) baseS[SNB] = cnt;
  }
  __syncthreads();
  // cursors start at local bases
  for (int b = t; b < DNB; b += TPBS) curD[b] = baseD[b];
  for (int b = t; b < SNB; b += TPBS) curS[b] = baseS[b];
  __syncthreads();

  // LDS scatter: block-local bucket-sorted staging
#pragma unroll
  for (int j = 0; j < EPT; ++j) {
    if (ed[j] >= 0) {
      int p = atomicAdd(&curD[ed[j] >> DSH], 1);
      pack_lds[p] = (es[j] << DSH) | (ed[j] & (DCB - 1));
      int q = atomicAdd(&curS[es[j] >> SSH], 1);
      ss_lds[q] = (unsigned short)(es[j] & (SCB - 1));
    }
  }
  __syncthreads();

  // burst flush: element i -> bucket via binary search on baseD/baseS;
  // consecutive i within a bucket hit consecutive global addresses.
  for (int i = t; i < cnt; i += TPBS) {
    int lo = 0, hi = DNB;
    while (hi - lo > 1) { int mid = (lo + hi) >> 1; if (baseD[mid] <= i) lo = mid; else hi = mid; }
    packed[Hsc[lo * NBLK + k] + (i - baseD[lo])] = pack_lds[i];
  }
  for (int i = t; i < cnt; i += TPBS) {
    int lo = 0, hi = SNB;
    while (hi - lo > 1) { int mid = (lo + hi) >> 1; if (baseS[mid] <= i) lo = mid; else hi = mid; }
    ss[Hsc[HLD + lo * NBLK + k] + (i - baseS[lo]) - NE] = ss_lds[i];
  }
}

// ------ D: per-bucket fine counting sort (dst) -> src_sorted/row_ptr/norm_in
__global__ __launch_bounds__(TPB) void k_fine_sort(const int* __restrict__ Hsc,
                                                   const int* __restrict__ packed,
                                                   int* __restrict__ src_sorted,
                                                   int* __restrict__ row_ptr,
                                                   float* __restrict__ norm_in) {
  __shared__ int hist[DCB], scn[DCB], cur[DCB];
  __shared__ int pool[POOL];
  int t = threadIdx.x, b = blockIdx.x;
  int seg_beg = Hsc[b * NBLK];
  int seg_end = (b + 1 < DNB) ? Hsc[(b + 1) * NBLK] : NE;
  int cnt = seg_end - seg_beg;
  hist[t] = 0;
  __syncthreads();
  for (int i = seg_beg + t; i < seg_end; i += TPB)
    atomicAdd(&hist[packed[i] & (DCB - 1)], 1);
  __syncthreads();
  scn[t] = hist[t];
  __syncthreads();
  for (int off = 1; off < DCB; off <<= 1) {   // Hillis-Steele inclusive (256=TPB)
    int add = (t >= off) ? scn[t - off] : 0;
    __syncthreads();
    scn[t] += add;
    __syncthreads();
  }
  {
    int excl = scn[t] - hist[t];
    cur[t] = excl;
    int node = b * DCB + t;
    if (node < NN) {
      row_ptr[node] = seg_beg + excl;
      norm_in[node] = (hist[t] > 0) ? rsqrtf((float)hist[t]) : 0.0f;
    }
  }
  if (b == DNB - 1 && t == 0) row_ptr[NN] = NE;
  __syncthreads();
  for (int i = seg_beg + t; i < seg_end; i += TPB) {
    int v = packed[i];
    int p = atomicAdd(&cur[v & (DCB - 1)], 1);
    int sv = v >> DSH;
    if (p < POOL) pool[p] = sv;
    else src_sorted[seg_beg + p] = sv;                 // overflow fallback (rare)
  }
  __syncthreads();
  int lim = min(cnt, POOL);
  for (int i = t; i < lim; i += TPB) src_sorted[seg_beg + i] = pool[i];
}

// ------ E: per-bucket fine count (src, 1024 bins) -> norm_out ---------------
__global__ __launch_bounds__(TPB) void k_fine_count(const int* __restrict__ Hsc,
                                                    const unsigned short* __restrict__ ss,
                                                    float* __restrict__ norm_out) {
  __shared__ int hist[SCB];
  int t = threadIdx.x, b = blockIdx.x;
  int seg_beg = Hsc[HLD + b * NBLK] - NE;
  int seg_end = (b + 1 < SNB) ? Hsc[HLD + (b + 1) * NBLK] - NE : NE;
  for (int i = t; i < SCB; i += TPB) hist[i] = 0;
  __syncthreads();
  for (int i = seg_beg + t; i < seg_end; i += TPB)
    atomicAdd(&hist[ss[i]], 1);
  __syncthreads();
  for (int i = t; i < SCB; i += TPB) {
    int node = b * SCB + i;
    if (node < NN)
      norm_out[node] = (hist[i] > 0) ? rsqrtf((float)hist[i]) : 0.0f;
  }
}

// ------ GEMM1: xt_b[n] = bf16( norm_out[n] * (x[n] @ W1) )  [64 -> 64] ------
__global__ __launch_bounds__(TPB) void k_gemm1(const float4* __restrict__ x4,
                                               const float* __restrict__ W1,
                                               const float* __restrict__ norm_out,
                                               unsigned short* __restrict__ xt_b) {
  int lane = threadIdx.x & 63;
  int wid = (blockIdx.x * TPB + threadIdx.x) >> 6;
  int nwaves = gridDim.x * (TPB / 64);
  float w[64];
#pragma unroll
  for (int k = 0; k < 64; ++k) w[k] = W1[k * 64 + lane];
  int m = lane >> 4, q = lane & 15;
  for (int grp = wid; grp < NN / 4; grp += nwaves) {
    int nbase = grp * 4;
    float4 rv = x4[(nbase + m) * 16 + q];
    int r0 = __float_as_int(rv.x), r1 = __float_as_int(rv.y);
    int r2 = __float_as_int(rv.z), r3 = __float_as_int(rv.w);
    float acc[4] = {0.f, 0.f, 0.f, 0.f};
#pragma unroll
    for (int mm = 0; mm < 4; ++mm) {
#pragma unroll
      for (int ql = 0; ql < 16; ++ql) {
        int sl = mm * 16 + ql;
        acc[mm] = fmaf(__int_as_float(__builtin_amdgcn_readlane(r0, sl)), w[ql * 4 + 0], acc[mm]);
        acc[mm] = fmaf(__int_as_float(__builtin_amdgcn_readlane(r1, sl)), w[ql * 4 + 1], acc[mm]);
        acc[mm] = fmaf(__int_as_float(__builtin_amdgcn_readlane(r2, sl)), w[ql * 4 + 2], acc[mm]);
        acc[mm] = fmaf(__int_as_float(__builtin_amdgcn_readlane(r3, sl)), w[ql * 4 + 3], acc[mm]);
      }
    }
#pragma unroll
    for (int mm = 0; mm < 4; ++mm) {
      int n = nbase + mm;
      xt_b[n * 64 + lane] = f2bf(norm_out[n] * acc[mm]);  // 128B/row coalesced
    }
  }
}

// -- AGG1+GEMM2 fused, wave-local: per node (grid-stride, 1 node per wave):
//    h1 = relu(norm_in*segsum(xt_b[src]) + b1)          [lean 2-deep gather]
//    h1t_b[n][0:32] = bf16(norm_out * (h1 @ W2))        [shfl+LDS epilogue]
__global__ __launch_bounds__(TPB) void k_agg1f(const uint4* __restrict__ xt4,
                                               const int* __restrict__ src_sorted,
                                               const int* __restrict__ row_ptr,
                                               const float* __restrict__ norm_in,
                                               const float* __restrict__ norm_out,
                                               const float* __restrict__ b1,
                                               const float* __restrict__ W2,
                                               unsigned short* __restrict__ h1t_b) {
  __shared__ float W2s[64][32];                // 8KB; [f][oc], cols 30,31 = 0
  int t = threadIdx.x;
  for (int i = t; i < 64 * 32; i += TPB) {
    int r = i >> 5, c = i & 31;
    W2s[r][c] = (c < NOUTF) ? W2[r * NOUTF + c] : 0.f;
  }
  __syncthreads();                             // once per block; node loop is barrier-free

  int lane = t & 63;
  int slot = lane >> 3;         // 0..7 edge slots
  int fl = lane & 7;            // uint4 index within 128B row
  int oc = lane & 31;
  int half = lane & 32;         // 0 | 32 : which k-half this lane covers
  int gwave = (blockIdx.x * TPB + t) >> 6;
  int nwaves = gridDim.x * (TPB / 64);

  // per-lane bias slice for features fl*8 .. fl*8+7 (loaded once)
  const float4* b1_4 = reinterpret_cast<const float4*>(b1);
  float4 bl = b1_4[fl * 2];
  float4 bh = b1_4[fl * 2 + 1];
  float b1r[8] = {bl.x, bl.y, bl.z, bl.w, bh.x, bh.y, bh.z, bh.w};

  for (int node = gwave; node < NN; node += nwaves) {
    int beg = row_ptr[node];
    int end = row_ptr[node + 1];
    float a[8] = {0.f, 0.f, 0.f, 0.f, 0.f, 0.f, 0.f, 0.f};
    int e = beg + slot;
    for (; e + 8 < end; e += 16) {             // lean 2-deep (r7-proven)
      int s0 = src_sorted[e];
      int s1 = src_sorted[e + 8];
      uint4 u0 = xt4[s0 * 8 + fl];
      uint4 u1 = xt4[s1 * 8 + fl];
      acc8(a, u0);
      acc8(a, u1);
    }
    if (e < end) {
      uint4 u0 = xt4[src_sorted[e] * 8 + fl];
      acc8(a, u0);
    }
#pragma unroll
    for (int off = 8; off <= 32; off <<= 1) {  // after this, EVERY lane holds
#pragma unroll
      for (int j = 0; j < 8; ++j) a[j] += __shfl_xor(a[j], off);
    }                                          // full sums for its fl group
    float ni = norm_in[node];
    float no = norm_out[node];
#pragma unroll
    for (int j = 0; j < 8; ++j)                // bias + relu in-lane
      a[j] = fmaxf(fmaf(a[j], ni, b1r[j]), 0.f);

    // h1 @ W2: lane covers output col oc for k in [half, half+32)
    float accv = 0.f;
#pragma unroll
    for (int kk = 0; kk < 32; ++kk) {
      int f = kk + half;                       // per-lane feature index
      float hv = __shfl(a[kk & 7], f >> 3);    // broadcast h1[f]
      accv = fmaf(hv, W2s[f][oc], accv);       // 2-way LDS (free)
    }
    accv += __shfl_xor(accv, 32);              // combine k-halves
    if (lane < 32) {
      unsigned short v = (oc < NOUTF) ? f2bf(no * accv) : (unsigned short)0;
      h1t_b[node * 32 + oc] = v;               // 64B/wave coalesced
    }
  }
}

// -- AGG2: out[n] = norm_in[n]*segsum(h1t_b[src]) + b2; bf16 in, f32 out -----
__global__ __launch_bounds__(TPB) void k_agg2(const uint4* __restrict__ h1t4,
                                              const int* __restrict__ src_sorted,
                                              const int* __restrict__ row_ptr,
                                              const float* __restrict__ norm_in,
                                              const float* __restrict__ b2,
                                              float* __restrict__ out) {
  int node = (blockIdx.x * TPB + threadIdx.x) >> 6;
  int lane = threadIdx.x & 63;
  int slot = lane >> 2;  // 0..15
  int fl = lane & 3;     // uint4 index within 64B row
  int beg = row_ptr[node];
  int end = row_ptr[node + 1];
  float a[8] = {0.f, 0.f, 0.f, 0.f, 0.f, 0.f, 0.f, 0.f};
  int e = beg + slot;
  for (; e + 16 < end; e += 32) {
    int s0 = src_sorted[e];
    int s1 = src_sorted[e + 16];
    uint4 u0 = h1t4[s0 * 4 + fl];
    uint4 u1 = h1t4[s1 * 4 + fl];
    acc8(a, u0);
    acc8(a, u1);
  }
  if (e < end) {
    uint4 u0 = h1t4[src_sorted[e] * 4 + fl];
    acc8(a, u0);
  }
#pragma unroll
  for (int off = 4; off <= 32; off <<= 1) {
#pragma unroll
    for (int j = 0; j < 8; ++j) a[j] += __shfl_xor(a[j], off);
  }
  if (slot == 0) {
    float ni = norm_in[node];
    int f0 = fl * 8;
    float2* ob = (float2*)(out + (size_t)node * NOUTF);  // rows 120B, 8B-aligned
#pragma unroll
    for (int p = 0; p < 4; ++p) {
      int f = f0 + p * 2;
      if (f < NOUTF) {
        float2 v;
        v.x = fmaf(a[p * 2], ni, b2[f]);
        v.y = fmaf(a[p * 2 + 1], ni, b2[f + 1]);
        ob[f >> 1] = v;
      }
    }
  }
}

extern "C" void kernel_launch(void* const* d_in, const int* in_sizes, int n_in,
                              void* d_out, int out_size, void* d_ws, size_t ws_size,
                              hipStream_t stream) {
  (void)in_sizes; (void)n_in; (void)out_size; (void)ws_size;
  const float* x = (const float*)d_in[0];
  const int* src = (const int*)d_in[1];
  const int* dst = (const int*)d_in[2];
  const float* W1 = (const float*)d_in[3];
  const float* b1 = (const float*)d_in[4];
  const float* W2 = (const float*)d_in[5];
  const float* b2 = (const float*)d_in[6];
  float* out = (float*)d_out;

  // Workspace layout (bytes); offsets 16B-aligned.
  // packed (12.8MB) dead after k_fine_sort -> h1t_b (6.4MB bf16) aliases it
  // (h1t_b must NOT alias xt_b: k_agg1f reads xt_b while writing h1t_b).
  char* ws = (char*)d_ws;
  int* row_ptr = (int*)(ws + 0);                           //    400,128
  float* norm_out = (float*)(ws + 400128);                 //    400,000
  float* norm_in = (float*)(ws + 800128);                  //    400,000
  int* H = (int*)(ws + 1200128);                           //    764,800 (HLT ints pad)
  int* bsums = (int*)(ws + 1964928);                       //        768 (NSC ints pad)
  unsigned short* ss = (unsigned short*)(ws + 1965696);    //  6,400,000
  int* src_sorted = (int*)(ws + 8365696);                  // 12,800,000
  int* packed = (int*)(ws + 21165696);                     // 12,800,000
  unsigned short* h1t_b = (unsigned short*)(ws + 21165696);// 6,400,000 (aliases packed)
  unsigned short* xt_b = (unsigned short*)(ws + 46765696); // 12,800,000

  k_hist<<<NBLK, TPBW, 0, stream>>>(src, dst, H);
  g_scan1<<<NSC, TPB, 0, stream>>>(H, bsums);
  g_scan2<<<1, 1024, 0, stream>>>(bsums);
  g_scan3<<<NSC, TPB, 0, stream>>>(H, bsums);
  k_scatter<<<NBLK, TPBS, 0, stream>>>(src, dst, H, packed, ss);
  k_fine_sort<<<DNB, TPB, 0, stream>>>(H, packed, src_sorted, row_ptr, norm_in);
  k_fine_count<<<SNB, TPB, 0, stream>>>(H, ss, norm_out);
  k_gemm1<<<1024, TPB, 0, stream>>>((const float4*)x, W1, norm_out, xt_b);
  k_agg1f<<<AGG1_BLOCKS, TPB, 0, stream>>>((const uint4*)xt_b, src_sorted, row_ptr,
                                           norm_in, norm_out, b1, W2, h1t_b);
  k_agg2<<<NN / 4, TPB, 0, stream>>>((const uint4*)h1t_b, src_sorted, row_ptr, norm_in, b2, out);
}